// Round 2
// baseline (1186.898 us; speedup 1.0000x reference)
//
#include <hip/hip_runtime.h>
#include <hip/hip_bf16.h>

typedef __bf16 bf16;
typedef __bf16 bf16x8 __attribute__((ext_vector_type(8)));
typedef __bf16 bf16x4 __attribute__((ext_vector_type(4)));
typedef __bf16 bf16x2 __attribute__((ext_vector_type(2)));
typedef float f32x4 __attribute__((ext_vector_type(4)));
typedef float f32x2 __attribute__((ext_vector_type(2)));

#define BATCH 32
#define N_ID 1024
#define L_IN 512

static const long ACT_E = (long)BATCH * N_ID * L_IN;   // 16,777,216 elems per activation
static const long S_NL  = (long)N_ID * L_IN;           // 524288
static const long S_TT  = (long)N_ID * N_ID;           // 1048576
static const long S_SS2 = (long)L_IN * L_IN;           // 262144

__device__ __forceinline__ void gload16(const bf16* g, bf16* l)
{
    __builtin_amdgcn_global_load_lds((__attribute__((address_space(1))) void*)g,
                                     (__attribute__((address_space(3))) void*)l, 16, 0, 0);
}

// ---------------------------------------------------------------------------
// 256x256 8-phase NT GEMM (T1..T5 stack): C[m,n] = sum_k A[m,k]*B[n,k]
// lda=ldb=K, ldc=N, batched via z.
// EPI: 0 bf16=acc+biasCol[n]; 1 bf16=acc+biasRow[m]; 2 f32=acc*scale;
//      3 bf16=acc; 4 bf16=acc*scal2[0]+scal2[1];
//      5 f32=acc+ResF32[m,n]+biasCol[n]; 6 f32=acc+ResBF16[m,n]+biasCol[n]
// ---------------------------------------------------------------------------
#define DS_RDS(BUF, MH, NH) \
    { \
_Pragma("unroll") \
      for (int i = 0; i < 4; ++i) { \
        const int rlA = wm * 64 + i * 16 + fr; \
_Pragma("unroll") \
        for (int ks = 0; ks < 2; ++ks) \
          af[i][ks] = *(const bf16x8*)&lds[BUF][0][MH][rlA * 64 + (((ks * 4 + kg) ^ (fr & 7)) * 8)]; \
      } \
_Pragma("unroll") \
      for (int j = 0; j < 2; ++j) { \
        const int rlB = wn * 32 + j * 16 + fr; \
_Pragma("unroll") \
        for (int ks = 0; ks < 2; ++ks) \
          bfv[j][ks] = *(const bf16x8*)&lds[BUF][1][NH][rlB * 64 + (((ks * 4 + kg) ^ (fr & 7)) * 8)]; \
      } \
    }

#define MFMA16(MH, NH) \
    { __builtin_amdgcn_s_setprio(1); \
_Pragma("unroll") \
      for (int i = 0; i < 4; ++i) \
_Pragma("unroll") \
        for (int j = 0; j < 2; ++j) { \
          acc[MH][NH][i][j] = __builtin_amdgcn_mfma_f32_16x16x32_bf16(af[i][0], bfv[j][0], acc[MH][NH][i][j], 0, 0, 0); \
          acc[MH][NH][i][j] = __builtin_amdgcn_mfma_f32_16x16x32_bf16(af[i][1], bfv[j][1], acc[MH][NH][i][j], 0, 0, 0); \
        } \
      __builtin_amdgcn_s_setprio(0); }

#define LGKM0 do { asm volatile("s_waitcnt lgkmcnt(0)" ::: "memory"); __builtin_amdgcn_sched_barrier(0); } while (0)
#define VM6   asm volatile("s_waitcnt vmcnt(6)" ::: "memory")
#define BAR   __builtin_amdgcn_s_barrier()

template<int EPI>
__global__ __launch_bounds__(512, 2)
void gemm8(const bf16* __restrict__ A, const bf16* __restrict__ Bm, void* __restrict__ Cout,
           const float* __restrict__ biasCol, const float* __restrict__ biasRow,
           const void* __restrict__ Res, const float* __restrict__ scal2,
           float scale, int M, int N, int K,
           long sA, long sB, long sC, long sRes)
{
    // [buf][A=0/B=1][half][16KB region]; regions grouped (wave-chunk-major) so
    // each phase frees exactly one region.
    __shared__ __align__(16) bf16 lds[2][2][2][8192];

    const int t = threadIdx.x;
    const int w = t >> 6;
    const int lane = t & 63;
    const int fr = lane & 15;
    const int kg = lane >> 4;
    const int wm = w >> 2;     // 2 M-waves
    const int wn = w & 3;      // 4 N-waves
    const long z = blockIdx.z;
    const long m0 = (long)blockIdx.x * 256;
    const long n0 = (long)blockIdx.y * 256;
    const bf16* Ab = A + z * sA;
    const bf16* Bb = Bm + z * sB;

    const int srow = w * 8 + (lane >> 3);          // 0..63 (row within 64-row chunk)
    const int clog = (lane & 7) ^ ((lane >> 3) & 7); // pre-swizzled global k-chunk

    // Stage one 16KB A-region (rows: [r*128 + half*64, +64)), linear LDS dest,
    // swizzle applied on the global source k-chunk (rule #21 involution).
    auto stA = [&](int buf, int half, int kt) {
#pragma unroll
        for (int r = 0; r < 2; ++r) {
            const bf16* src = Ab + (long)(m0 + r * 128 + half * 64 + srow) * K + kt * 64 + clog * 8;
            gload16(src, (bf16*)&lds[buf][0][half][r * 4096 + w * 512 + lane * 8]);
        }
    };
    // B-region rows: wn' = r*2 + (w>>2); col32 = (w&3)*8 + lane/8
    auto stB = [&](int buf, int half, int kt) {
#pragma unroll
        for (int r = 0; r < 2; ++r) {
            const int nrow = (r * 2 + (w >> 2)) * 64 + half * 32 + (w & 3) * 8 + (lane >> 3);
            const bf16* src = Bb + (long)(n0 + nrow) * K + kt * 64 + clog * 8;
            gload16(src, (bf16*)&lds[buf][1][half][r * 4096 + w * 512 + lane * 8]);
        }
    };

    f32x4 acc[2][2][4][2] = {};
    bf16x8 af[4][2];
    bf16x8 bfv[2][2];

    // Prologue: buf0 <- kt0 (4 regions), plus P7/P8-equivalents of buf1 <- kt1.
    stA(0, 0, 0); stA(0, 1, 0); stB(0, 0, 0); stB(0, 1, 0);
    stB(1, 0, 1); stA(1, 1, 1);

    const int NT = K >> 6;
    for (int it = 0; it < (NT >> 1); ++it) {
        const int k1 = 2 * it + 1;
        int k2 = 2 * it + 2; if (k2 >= NT) k2 -= NT;   // wrap: harmless redundant stage
        int k3 = 2 * it + 3; if (k3 >= NT) k3 -= NT;

        // P1: buf0 quad (0,0) | stage A1a<-k1 (freed prev P8) | confirm buf0
        stA(1, 0, k1);
        VM6; BAR;
        DS_RDS(0, 0, 0); LGKM0;
        MFMA16(0, 0);
        BAR;
        // P2: buf0 (1,0) | stage B1b<-k1 (freed prev P8)
        DS_RDS(0, 1, 0);
        stB(1, 1, k1);
        BAR; LGKM0;
        MFMA16(1, 0);
        BAR;
        // P3: buf0 (1,1) | stage B0a<-k2 (freed P2)
        DS_RDS(0, 1, 1);
        stB(0, 0, k2);
        BAR; LGKM0;
        MFMA16(1, 1);
        BAR;
        // P4: buf0 (0,1) | stage A0b<-k2 (freed P3)
        DS_RDS(0, 0, 1);
        stA(0, 1, k2);
        BAR; LGKM0;
        MFMA16(0, 1);
        BAR;
        // P5: buf1 (0,0) | stage A0a<-k2 (freed P4) | confirm buf1
        stA(0, 0, k2);
        VM6; BAR;
        DS_RDS(1, 0, 0); LGKM0;
        MFMA16(0, 0);
        BAR;
        // P6: buf1 (1,0) | stage B0b<-k2 (freed P4)
        DS_RDS(1, 1, 0);
        stB(0, 1, k2);
        BAR; LGKM0;
        MFMA16(1, 0);
        BAR;
        // P7: buf1 (1,1) | stage B1a<-k3 (freed P6)
        DS_RDS(1, 1, 1);
        stB(1, 0, k3);
        BAR; LGKM0;
        MFMA16(1, 1);
        BAR;
        // P8: buf1 (0,1) | stage A1b<-k3 (freed P7)
        DS_RDS(1, 0, 1);
        stA(1, 1, k3);
        BAR; LGKM0;
        MFMA16(0, 1);
        BAR;
    }

    float e0 = 0.f, e1 = 0.f;
    if constexpr (EPI == 4) { e0 = scal2[0]; e1 = scal2[1]; }

#pragma unroll
    for (int mH = 0; mH < 2; ++mH)
#pragma unroll
    for (int i = 0; i < 4; ++i)
#pragma unroll
    for (int nH = 0; nH < 2; ++nH)
#pragma unroll
    for (int j = 0; j < 2; ++j)
#pragma unroll
    for (int r = 0; r < 4; ++r) {
        const long rr = m0 + wm * 128 + mH * 64 + i * 16 + kg * 4 + r;
        const long cc = n0 + wn * 64 + nH * 32 + j * 16 + fr;
        const float v = acc[mH][nH][i][j][r];
        const long idx = z * sC + rr * (long)N + cc;
        if constexpr (EPI == 0)      ((bf16*)Cout)[idx] = (bf16)(v + biasCol[cc]);
        else if constexpr (EPI == 1) ((bf16*)Cout)[idx] = (bf16)(v + biasRow[rr]);
        else if constexpr (EPI == 2) ((float*)Cout)[idx] = v * scale;
        else if constexpr (EPI == 3) ((bf16*)Cout)[idx] = (bf16)v;
        else if constexpr (EPI == 4) ((bf16*)Cout)[idx] = (bf16)(v * e0 + e1);
        else if constexpr (EPI == 5) ((float*)Cout)[idx] = v + ((const float*)Res)[z * sRes + rr * (long)N + cc] + biasCol[cc];
        else                         ((float*)Cout)[idx] = v + (float)((const bf16*)Res)[z * sRes + rr * (long)N + cc] + biasCol[cc];
    }
}

// ---------------------------------------------------------------------------
// Row softmax: fp32 in (scale pre-applied), bf16 out. One 256-thread block/row.
// ---------------------------------------------------------------------------
template<int W>
__global__ __launch_bounds__(256)
void softmax_rows(const float* __restrict__ S, bf16* __restrict__ P)
{
    constexpr int NV = W / 256;
    const long row = blockIdx.x;
    const int t = threadIdx.x;
    const float* src = S + row * (long)W + t * NV;
    bf16* dst = P + row * (long)W + t * NV;

    float v[NV];
    if constexpr (NV == 4) { f32x4 x = *(const f32x4*)src; v[0]=x[0]; v[1]=x[1]; v[2]=x[2]; v[3]=x[3]; }
    else                   { f32x2 x = *(const f32x2*)src; v[0]=x[0]; v[1]=x[1]; }

    float m = v[0];
#pragma unroll
    for (int i = 1; i < NV; ++i) m = fmaxf(m, v[i]);
#pragma unroll
    for (int o = 32; o > 0; o >>= 1) m = fmaxf(m, __shfl_xor(m, o));
    __shared__ float red[8];
    const int w = t >> 6, l = t & 63;
    if (l == 0) red[w] = m;
    __syncthreads();
    m = fmaxf(fmaxf(red[0], red[1]), fmaxf(red[2], red[3]));

    float s = 0.f;
#pragma unroll
    for (int i = 0; i < NV; ++i) { v[i] = __expf(v[i] - m); s += v[i]; }
#pragma unroll
    for (int o = 32; o > 0; o >>= 1) s += __shfl_xor(s, o);
    if (l == 0) red[4 + w] = s;
    __syncthreads();
    s = red[4] + red[5] + red[6] + red[7];
    const float inv = 1.f / s;

    if constexpr (NV == 4) {
        bf16x4 o4;
#pragma unroll
        for (int i = 0; i < 4; ++i) o4[i] = (bf16)(v[i] * inv);
        *(bf16x4*)dst = o4;
    } else {
        bf16x2 o2;
#pragma unroll
        for (int i = 0; i < 2; ++i) o2[i] = (bf16)(v[i] * inv);
        *(bf16x2*)dst = o2;
    }
}

// ---------------------------------------------------------------------------
// LayerNorm over rows of 512 (f32 in). OUTBF=1 -> bf16 out, else f32 out.
// ---------------------------------------------------------------------------
template<int OUTBF>
__global__ __launch_bounds__(128)
void ln_rows(const float* __restrict__ X, const float* __restrict__ g,
             const float* __restrict__ bta, void* __restrict__ out)
{
    const long row = blockIdx.x;
    const int t = threadIdx.x;
    f32x4 v = *(const f32x4*)(X + row * 512 + t * 4);
    float s1 = v[0] + v[1] + v[2] + v[3];
    float s2 = v[0]*v[0] + v[1]*v[1] + v[2]*v[2] + v[3]*v[3];
#pragma unroll
    for (int o = 32; o > 0; o >>= 1) { s1 += __shfl_xor(s1, o); s2 += __shfl_xor(s2, o); }
    __shared__ float r1[2], r2[2];
    const int w = t >> 6, l = t & 63;
    if (l == 0) { r1[w] = s1; r2[w] = s2; }
    __syncthreads();
    s1 = r1[0] + r1[1];
    s2 = r2[0] + r2[1];
    const float mean = s1 * (1.f / 512.f);
    const float var  = s2 * (1.f / 512.f) - mean * mean;
    const float rstd = rsqrtf(var + 1e-5f);
    const int c = t * 4;
    if constexpr (OUTBF) {
        bf16x4 o4;
#pragma unroll
        for (int k = 0; k < 4; ++k) o4[k] = (bf16)((v[k] - mean) * rstd * g[c + k] + bta[c + k]);
        *(bf16x4*)((bf16*)out + row * 512 + c) = o4;
    } else {
        f32x4 o4;
#pragma unroll
        for (int k = 0; k < 4; ++k) o4[k] = (v[k] - mean) * rstd * g[c + k] + bta[c + k];
        *(f32x4*)((float*)out + row * 512 + c) = o4;
    }
}

// ---------------------------------------------------------------------------
__global__ __launch_bounds__(256)
void transpose_cvt(const float* __restrict__ x, bf16* __restrict__ Xb, bf16* __restrict__ xt)
{
    __shared__ bf16 tile[32][33];
    const int b = blockIdx.z;
    const int n0 = blockIdx.x * 32, l0 = blockIdx.y * 32;
    const long base = (long)b * N_ID * L_IN;
    const int tx = threadIdx.x, ty = threadIdx.y;
#pragma unroll
    for (int i = ty; i < 32; i += 8) {
        const long idx = base + (long)(n0 + i) * L_IN + l0 + tx;
        const bf16 s = (bf16)x[idx];
        Xb[idx] = s;
        tile[i][tx] = s;
    }
    __syncthreads();
#pragma unroll
    for (int i = ty; i < 32; i += 8)
        xt[base + (long)(l0 + i) * N_ID + n0 + tx] = tile[tx][i];
}

__global__ void cvt_bf16(const float* __restrict__ in, bf16* __restrict__ out, int n)
{
    const int i = blockIdx.x * 256 + threadIdx.x;
    if (i < n) out[i] = (bf16)in[i];
}

__global__ void wo_sum(const float* __restrict__ Wo, bf16* __restrict__ out)
{
    const int i = blockIdx.x * 256 + threadIdx.x; // < 262144
    const float* p = Wo + (long)i * 8;
    float s = 0.f;
#pragma unroll
    for (int h = 0; h < 8; ++h) s += p[h];
    out[i] = (bf16)s;
}

__global__ void prep_scal(const float* __restrict__ W1, const float* __restrict__ b1, float* __restrict__ out)
{
    if (threadIdx.x == 0 && blockIdx.x == 0) {
        float s = 0.f;
        for (int h = 0; h < 8; ++h) s += W1[h];
        out[0] = s;
        out[1] = b1[0];
    }
}

// ---------------------------------------------------------------------------
static void launch_gemm(int epi, const bf16* A, const bf16* B, void* C,
                        const float* bc, const float* br, const void* res, const float* sc2,
                        float scale, int M, int N, int K,
                        long sA, long sB, long sC, long sRes, int batches, hipStream_t st)
{
    dim3 g(M / 256, N / 256, batches), blk(512);
    switch (epi) {
    case 0: gemm8<0><<<g, blk, 0, st>>>(A, B, C, bc, br, res, sc2, scale, M, N, K, sA, sB, sC, sRes); break;
    case 1: gemm8<1><<<g, blk, 0, st>>>(A, B, C, bc, br, res, sc2, scale, M, N, K, sA, sB, sC, sRes); break;
    case 2: gemm8<2><<<g, blk, 0, st>>>(A, B, C, bc, br, res, sc2, scale, M, N, K, sA, sB, sC, sRes); break;
    case 3: gemm8<3><<<g, blk, 0, st>>>(A, B, C, bc, br, res, sc2, scale, M, N, K, sA, sB, sC, sRes); break;
    case 4: gemm8<4><<<g, blk, 0, st>>>(A, B, C, bc, br, res, sc2, scale, M, N, K, sA, sB, sC, sRes); break;
    case 5: gemm8<5><<<g, blk, 0, st>>>(A, B, C, bc, br, res, sc2, scale, M, N, K, sA, sB, sC, sRes); break;
    default: gemm8<6><<<g, blk, 0, st>>>(A, B, C, bc, br, res, sc2, scale, M, N, K, sA, sB, sC, sRes); break;
    }
}

extern "C" void kernel_launch(void* const* d_in, const int* in_sizes, int n_in,
                              void* d_out, int out_size, void* d_ws, size_t ws_size,
                              hipStream_t stream)
{
    (void)in_sizes; (void)n_in; (void)out_size;

    const float* x   = (const float*)d_in[0];
    const float* tWq = (const float*)d_in[1];  const float* tbq = (const float*)d_in[2];
    const float* tWk = (const float*)d_in[3];  const float* tbk = (const float*)d_in[4];
    const float* tWv = (const float*)d_in[5];  const float* tbv = (const float*)d_in[6];
    const float* tWo = (const float*)d_in[7];  const float* tbo = (const float*)d_in[8];
    const float* tg  = (const float*)d_in[9];  const float* tb  = (const float*)d_in[10];
    const float* cWq = (const float*)d_in[11]; const float* cbq = (const float*)d_in[12];
    const float* cWk = (const float*)d_in[13]; const float* cbk = (const float*)d_in[14];
    const float* cWv = (const float*)d_in[15]; const float* cbv = (const float*)d_in[16];
    const float* cWo = (const float*)d_in[17]; const float* cbo = (const float*)d_in[18];
    const float* cg  = (const float*)d_in[19]; const float* cb  = (const float*)d_in[20];
    const float* sWq = (const float*)d_in[21]; const float* sbq = (const float*)d_in[22];
    const float* sWk = (const float*)d_in[23]; const float* sbk = (const float*)d_in[24];
    const float* sWv = (const float*)d_in[25]; const float* sbv = (const float*)d_in[26];
    const float* sW1 = (const float*)d_in[27]; const float* sb1 = (const float*)d_in[28];

    char* p = (char*)d_ws;
    auto alloc = [&](size_t bytes) -> char* {
        char* r = p; p += (bytes + 255) & ~(size_t)255; return r;
    };

    bf16* WqT = (bf16*)alloc(262144 * 2);  bf16* WkT = (bf16*)alloc(262144 * 2);  bf16* WvT = (bf16*)alloc(262144 * 2);
    bf16* WqC = (bf16*)alloc(262144 * 2);  bf16* WkC = (bf16*)alloc(262144 * 2);  bf16* WvC = (bf16*)alloc(262144 * 2);
    bf16* WqS = (bf16*)alloc(1048576 * 2); bf16* WkS = (bf16*)alloc(1048576 * 2); bf16* WvS = (bf16*)alloc(1048576 * 2);
    bf16* WsT = (bf16*)alloc(262144 * 2);  bf16* WsC = (bf16*)alloc(262144 * 2);
    float* scal = (float*)alloc(256);

    const size_t ACT_B = (size_t)ACT_E * 2;
    bf16* Xb   = (bf16*)alloc(ACT_B);   // reused as SO after stage T
    bf16* xt   = (bf16*)alloc(ACT_B);
    bf16* bufQ = (bf16*)alloc(ACT_B);   // Q; Lm aliases this in attn loops
    bf16* bufK = (bf16*)alloc(ACT_B);
    bf16* bufV = (bf16*)alloc(ACT_B);
    bf16* TO   = (bf16*)alloc(ACT_B);

    size_t used = (size_t)(p - (char*)d_ws);
    int CB = 32;
    while (CB > 1 && used + (size_t)CB * 1048576ULL * 6ULL + 4096 > ws_size) CB >>= 1;
    float* Sbuf = (float*)alloc((size_t)CB * 1048576ULL * 4ULL);
    bf16*  Pbuf = (bf16*)alloc((size_t)CB * 1048576ULL * 2ULL);

    const float rsc_t = 0.08838834764831845f;  // 1/sqrt(1024/8)
    const float rsc_s = 0.125f;                // 1/sqrt(512/8)

    // ---- prep ----
    cvt_bf16<<<dim3(1024), dim3(256), 0, stream>>>(tWq, WqT, 262144);
    cvt_bf16<<<dim3(1024), dim3(256), 0, stream>>>(tWk, WkT, 262144);
    cvt_bf16<<<dim3(1024), dim3(256), 0, stream>>>(tWv, WvT, 262144);
    cvt_bf16<<<dim3(1024), dim3(256), 0, stream>>>(cWq, WqC, 262144);
    cvt_bf16<<<dim3(1024), dim3(256), 0, stream>>>(cWk, WkC, 262144);
    cvt_bf16<<<dim3(1024), dim3(256), 0, stream>>>(cWv, WvC, 262144);
    cvt_bf16<<<dim3(4096), dim3(256), 0, stream>>>(sWq, WqS, 1048576);
    cvt_bf16<<<dim3(4096), dim3(256), 0, stream>>>(sWk, WkS, 1048576);
    cvt_bf16<<<dim3(4096), dim3(256), 0, stream>>>(sWv, WvS, 1048576);
    wo_sum<<<dim3(1024), dim3(256), 0, stream>>>(tWo, WsT);
    wo_sum<<<dim3(1024), dim3(256), 0, stream>>>(cWo, WsC);
    prep_scal<<<dim3(1), dim3(64), 0, stream>>>(sW1, sb1, scal);
    transpose_cvt<<<dim3(32, 16, BATCH), dim3(32, 8), 0, stream>>>(x, Xb, xt);

    auto attn_tc = [&](const bf16* Q, const bf16* Kb, const bf16* V, bf16* LmOut, float rsc) {
        for (int c0 = 0; c0 < BATCH; c0 += CB) {
            const long off = (long)c0 * S_NL;
            launch_gemm(2, Q + off, Kb + off, Sbuf, nullptr, nullptr, nullptr, nullptr, rsc,
                        1024, 1024, 512, S_NL, S_NL, S_TT, 0, CB, stream);
            softmax_rows<1024><<<dim3(CB * 1024), dim3(256), 0, stream>>>(Sbuf, Pbuf);
            launch_gemm(3, Pbuf, V + off, LmOut + off, nullptr, nullptr, nullptr, nullptr, 0.f,
                        1024, 512, 1024, S_TT, S_NL, S_NL, 0, CB, stream);
        }
    };

    // ==== Stage T (time de_att) ====
    launch_gemm(0, Xb, WqT, bufQ, tbq, nullptr, nullptr, nullptr, 0.f, 32768, 512, 512, 0, 0, 0, 0, 1, stream);
    launch_gemm(0, Xb, WkT, bufK, tbk, nullptr, nullptr, nullptr, 0.f, 32768, 512, 512, 0, 0, 0, 0, 1, stream);
    launch_gemm(1, WvT, Xb, bufV, nullptr, tbv, nullptr, nullptr, 0.f, 512, 1024, 512, 0, S_NL, S_NL, 0, BATCH, stream);
    attn_tc(bufQ, bufK, bufV, bufQ, rsc_t);
    launch_gemm(5, bufQ, WsT, d_out, tbo, nullptr, x, nullptr, 0.f, 32768, 512, 512, 0, 0, 0, 0, 1, stream);
    ln_rows<1><<<dim3(32768), dim3(128), 0, stream>>>((const float*)d_out, tg, tb, TO);

    // ==== Stage S (space attention) ====
    bf16* SOp = Xb;
    launch_gemm(0, xt, WqS, bufQ, sbq, nullptr, nullptr, nullptr, 0.f, 16384, 1024, 1024, 0, 0, 0, 0, 1, stream);
    launch_gemm(0, xt, WkS, bufK, sbk, nullptr, nullptr, nullptr, 0.f, 16384, 1024, 1024, 0, 0, 0, 0, 1, stream);
    launch_gemm(1, WvS, xt, bufV, nullptr, sbv, nullptr, nullptr, 0.f, 1024, 512, 1024, 0, S_NL, S_NL, 0, BATCH, stream);
    for (int c0 = 0; c0 < BATCH; c0 += CB) {
        const long off = (long)c0 * S_NL;
        launch_gemm(2, bufQ + off, bufK + off, Sbuf, nullptr, nullptr, nullptr, nullptr, rsc_s,
                    512, 512, 1024, S_NL, S_NL, S_SS2, 0, CB, stream);
        softmax_rows<512><<<dim3(CB * 512), dim3(256), 0, stream>>>(Sbuf, Pbuf);
        launch_gemm(4, bufV + off, Pbuf, SOp + off, nullptr, nullptr, nullptr, scal, 0.f,
                    1024, 512, 512, S_NL, S_SS2, S_NL, 0, CB, stream);
    }

    // ==== Stage C (cross de_att) ====
    launch_gemm(0, SOp, WqC, bufQ, cbq, nullptr, nullptr, nullptr, 0.f, 32768, 512, 512, 0, 0, 0, 0, 1, stream);
    launch_gemm(0, TO, WkC, bufK, cbk, nullptr, nullptr, nullptr, 0.f, 32768, 512, 512, 0, 0, 0, 0, 1, stream);
    launch_gemm(1, WvC, TO, bufV, nullptr, cbv, nullptr, nullptr, 0.f, 512, 1024, 512, 0, S_NL, S_NL, 0, BATCH, stream);
    attn_tc(bufQ, bufK, bufV, bufQ, rsc_t);
    launch_gemm(6, bufQ, WsC, d_out, cbo, nullptr, TO, nullptr, 0.f, 32768, 512, 512, 0, 0, 0, 0, 1, stream);
    ln_rows<0><<<dim3(32768), dim3(128), 0, stream>>>((const float*)d_out, cg, cb, d_out);
}

// Round 3
// 840.633 us; speedup vs baseline: 1.4119x; 1.4119x over previous
//
#include <hip/hip_runtime.h>
#include <hip/hip_bf16.h>

typedef __bf16 bf16;
typedef __bf16 bf16x8 __attribute__((ext_vector_type(8)));
typedef __bf16 bf16x4 __attribute__((ext_vector_type(4)));
typedef __bf16 bf16x2 __attribute__((ext_vector_type(2)));
typedef float f32x4 __attribute__((ext_vector_type(4)));
typedef float f32x2 __attribute__((ext_vector_type(2)));

#define BATCH 32
#define N_ID 1024
#define L_IN 512

static const long ACT_E = (long)BATCH * N_ID * L_IN;   // 16,777,216
static const long S_NL  = (long)N_ID * L_IN;           // 524288
static const long S_TT  = (long)N_ID * N_ID;           // 1048576
static const long S_SS2 = (long)L_IN * L_IN;           // 262144

__device__ __forceinline__ void gload16(const bf16* g, bf16* l)
{
    __builtin_amdgcn_global_load_lds((__attribute__((address_space(1))) void*)g,
                                     (__attribute__((address_space(3))) void*)l, 16, 0, 0);
}

// ---------------------------------------------------------------------------
// 256x256 2-phase counted-pipeline NT GEMM: C[m,n] = sum_k A[m,k]*B[n,k]
// lda=ldb=K, ldc=N, batch via swizzled 1-D grid. BK=64, 8 waves (2M x 4N).
// Schedule per K-tile: issue 8 global_load_lds (next tile) -> 32 ds_read_b128
// (fragment-reuse snake) + 64 MFMA -> vmcnt(0) -> s_barrier.  (T3-minimum)
// EPI: 0 bf16=acc+biasCol[n]; 1 bf16=acc+biasRow[m]; 2 bf16=acc*scale;
//      3 bf16=acc; 4 bf16=acc*scal2[0]+scal2[1];
//      5 f32=acc+ResF32+biasCol[n]; 6 f32=acc+ResBF16+biasCol[n]
// ---------------------------------------------------------------------------
#define LDA(BUF, MH) \
_Pragma("unroll") \
    for (int i = 0; i < 4; ++i) { \
      const int rlA = wm * 64 + i * 16 + fr; \
_Pragma("unroll") \
      for (int ks = 0; ks < 2; ++ks) \
        af[i][ks] = *(const bf16x8*)&lds[BUF][0][MH][rlA * 64 + (((ks * 4 + kg) ^ (fr & 7)) * 8)]; \
    }

#define LDB(BUF, NH) \
_Pragma("unroll") \
    for (int j = 0; j < 2; ++j) { \
      const int rlB = wn * 32 + j * 16 + fr; \
_Pragma("unroll") \
      for (int ks = 0; ks < 2; ++ks) \
        bfv[j][ks] = *(const bf16x8*)&lds[BUF][1][NH][rlB * 64 + (((ks * 4 + kg) ^ (fr & 7)) * 8)]; \
    }

#define MFMA16(MH, NH) \
_Pragma("unroll") \
    for (int i = 0; i < 4; ++i) \
_Pragma("unroll") \
      for (int j = 0; j < 2; ++j) { \
        acc[MH][NH][i][j] = __builtin_amdgcn_mfma_f32_16x16x32_bf16(af[i][0], bfv[j][0], acc[MH][NH][i][j], 0, 0, 0); \
        acc[MH][NH][i][j] = __builtin_amdgcn_mfma_f32_16x16x32_bf16(af[i][1], bfv[j][1], acc[MH][NH][i][j], 0, 0, 0); \
      }

#define STAGE(BUF, KT) { stA(BUF, 0, KT); stA(BUF, 1, KT); stB(BUF, 0, KT); stB(BUF, 1, KT); }

#define COMPUTE(BUF) \
    { LDA(BUF, 0); LDB(BUF, 0); MFMA16(0, 0); \
      LDA(BUF, 1);              MFMA16(1, 0); \
      LDB(BUF, 1);              MFMA16(1, 1); \
      LDA(BUF, 0);              MFMA16(0, 1); }

#define VM0 asm volatile("s_waitcnt vmcnt(0)" ::: "memory")
#define BAR __builtin_amdgcn_s_barrier()

template<int EPI>
__global__ __launch_bounds__(512, 2)
void gemm2(const bf16* __restrict__ A, const bf16* __restrict__ Bm, void* __restrict__ Cout,
           const float* __restrict__ biasCol, const float* __restrict__ biasRow,
           const void* __restrict__ Res, const float* __restrict__ scal2,
           float scale, int N, int K,
           long sA, long sB, long sC, long sRes,
           unsigned gx, unsigned gxy, unsigned nwg)
{
    __shared__ __align__(16) bf16 lds[2][2][2][8192];  // [buf][A/B][half][16KB]

    // bijective XCD swizzle (m204): chunk the grid so each XCD owns
    // consecutive work (same B panel / same batch) -> L2 locality.
    unsigned id = blockIdx.x;
    {
        const unsigned q = nwg >> 3, r = nwg & 7;
        const unsigned xcd = id & 7, off = id >> 3;
        id = (xcd < r ? xcd * (q + 1) : r * (q + 1) + (xcd - r) * q) + off;
    }
    const unsigned bz = id / gxy;
    const unsigned rem = id - bz * gxy;
    const unsigned by = rem / gx;
    const unsigned bx = rem - by * gx;

    const int t = threadIdx.x;
    const int w = t >> 6;
    const int lane = t & 63;
    const int fr = lane & 15;
    const int kg = lane >> 4;
    const int wm = w >> 2;     // 2 M-waves
    const int wn = w & 3;      // 4 N-waves
    const long z = bz;
    const long m0 = (long)bx * 256;
    const long n0 = (long)by * 256;
    const bf16* Ab = A + z * sA;
    const bf16* Bb = Bm + z * sB;

    const int srow = w * 8 + (lane >> 3);            // staging row within 64-chunk
    const int clog = (lane & 7) ^ ((lane >> 3) & 7); // pre-swizzled global k-chunk

    auto stA = [&](int buf, int half, int kt) {
#pragma unroll
        for (int r = 0; r < 2; ++r) {
            const bf16* src = Ab + (long)(m0 + r * 128 + half * 64 + srow) * K + kt * 64 + clog * 8;
            gload16(src, (bf16*)&lds[buf][0][half][r * 4096 + w * 512 + lane * 8]);
        }
    };
    auto stB = [&](int buf, int half, int kt) {
#pragma unroll
        for (int r = 0; r < 2; ++r) {
            const int nrow = (r * 2 + (w >> 2)) * 64 + half * 32 + (w & 3) * 8 + (lane >> 3);
            const bf16* src = Bb + (long)(n0 + nrow) * K + kt * 64 + clog * 8;
            gload16(src, (bf16*)&lds[buf][1][half][r * 4096 + w * 512 + lane * 8]);
        }
    };

    f32x4 acc[2][2][4][2] = {};
    bf16x8 af[4][2];
    bf16x8 bfv[2][2];

    // prologue: tile 0 -> buf0, drain once, sync
    STAGE(0, 0);
    VM0; BAR;

    const int NT = K >> 6;            // K % 128 == 0 -> NT even
    for (int kt = 0; kt < NT; kt += 2) {
        // tile kt (buf0); prefetch kt+1 -> buf1
        if (kt + 1 < NT) STAGE(1, kt + 1);
        COMPUTE(0);
        VM0; BAR;
        // tile kt+1 (buf1); prefetch kt+2 -> buf0
        if (kt + 2 < NT) STAGE(0, kt + 2);
        COMPUTE(1);
        VM0; BAR;
    }

    float e0 = 0.f, e1 = 0.f;
    if constexpr (EPI == 4) { e0 = scal2[0]; e1 = scal2[1]; }

#pragma unroll
    for (int mH = 0; mH < 2; ++mH)
#pragma unroll
    for (int i = 0; i < 4; ++i)
#pragma unroll
    for (int nH = 0; nH < 2; ++nH)
#pragma unroll
    for (int j = 0; j < 2; ++j)
#pragma unroll
    for (int r = 0; r < 4; ++r) {
        const long rr = m0 + wm * 128 + mH * 64 + i * 16 + kg * 4 + r;
        const long cc = n0 + wn * 64 + nH * 32 + j * 16 + fr;
        const float v = acc[mH][nH][i][j][r];
        const long idx = z * sC + rr * (long)N + cc;
        if constexpr (EPI == 0)      ((bf16*)Cout)[idx] = (bf16)(v + biasCol[cc]);
        else if constexpr (EPI == 1) ((bf16*)Cout)[idx] = (bf16)(v + biasRow[rr]);
        else if constexpr (EPI == 2) ((bf16*)Cout)[idx] = (bf16)(v * scale);
        else if constexpr (EPI == 3) ((bf16*)Cout)[idx] = (bf16)v;
        else if constexpr (EPI == 4) ((bf16*)Cout)[idx] = (bf16)(v * e0 + e1);
        else if constexpr (EPI == 5) ((float*)Cout)[idx] = v + ((const float*)Res)[z * sRes + rr * (long)N + cc] + biasCol[cc];
        else                         ((float*)Cout)[idx] = v + (float)((const bf16*)Res)[z * sRes + rr * (long)N + cc] + biasCol[cc];
    }
}

// ---------------------------------------------------------------------------
// Row softmax, bf16 in -> bf16 out, IN-PLACE safe (P aliases S).
// Scale already applied by the QK^T epilogue.
// ---------------------------------------------------------------------------
template<int W>
__global__ __launch_bounds__(256)
void softmax_rows(const bf16* __restrict__ S, bf16* __restrict__ P)
{
    constexpr int NV = W / 256;
    const long row = blockIdx.x;
    const int t = threadIdx.x;
    const bf16* src = S + row * (long)W + t * NV;
    bf16* dst = P + row * (long)W + t * NV;

    float v[NV];
    if constexpr (NV == 4) { bf16x4 x = *(const bf16x4*)src;
        v[0] = (float)x[0]; v[1] = (float)x[1]; v[2] = (float)x[2]; v[3] = (float)x[3]; }
    else { bf16x2 x = *(const bf16x2*)src; v[0] = (float)x[0]; v[1] = (float)x[1]; }

    float m = v[0];
#pragma unroll
    for (int i = 1; i < NV; ++i) m = fmaxf(m, v[i]);
#pragma unroll
    for (int o = 32; o > 0; o >>= 1) m = fmaxf(m, __shfl_xor(m, o));
    __shared__ float red[8];
    const int w = t >> 6, l = t & 63;
    if (l == 0) red[w] = m;
    __syncthreads();
    m = fmaxf(fmaxf(red[0], red[1]), fmaxf(red[2], red[3]));

    float s = 0.f;
#pragma unroll
    for (int i = 0; i < NV; ++i) { v[i] = __expf(v[i] - m); s += v[i]; }
#pragma unroll
    for (int o = 32; o > 0; o >>= 1) s += __shfl_xor(s, o);
    if (l == 0) red[4 + w] = s;
    __syncthreads();
    s = red[4] + red[5] + red[6] + red[7];
    const float inv = 1.f / s;

    if constexpr (NV == 4) {
        bf16x4 o4;
#pragma unroll
        for (int i = 0; i < 4; ++i) o4[i] = (bf16)(v[i] * inv);
        *(bf16x4*)dst = o4;
    } else {
        bf16x2 o2;
#pragma unroll
        for (int i = 0; i < 2; ++i) o2[i] = (bf16)(v[i] * inv);
        *(bf16x2*)dst = o2;
    }
}

// ---------------------------------------------------------------------------
template<int OUTBF>
__global__ __launch_bounds__(128)
void ln_rows(const float* __restrict__ X, const float* __restrict__ g,
             const float* __restrict__ bta, void* __restrict__ out)
{
    const long row = blockIdx.x;
    const int t = threadIdx.x;
    f32x4 v = *(const f32x4*)(X + row * 512 + t * 4);
    float s1 = v[0] + v[1] + v[2] + v[3];
    float s2 = v[0]*v[0] + v[1]*v[1] + v[2]*v[2] + v[3]*v[3];
#pragma unroll
    for (int o = 32; o > 0; o >>= 1) { s1 += __shfl_xor(s1, o); s2 += __shfl_xor(s2, o); }
    __shared__ float r1[2], r2[2];
    const int w = t >> 6, l = t & 63;
    if (l == 0) { r1[w] = s1; r2[w] = s2; }
    __syncthreads();
    s1 = r1[0] + r1[1];
    s2 = r2[0] + r2[1];
    const float mean = s1 * (1.f / 512.f);
    const float var  = s2 * (1.f / 512.f) - mean * mean;
    const float rstd = rsqrtf(var + 1e-5f);
    const int c = t * 4;
    if constexpr (OUTBF) {
        bf16x4 o4;
#pragma unroll
        for (int k = 0; k < 4; ++k) o4[k] = (bf16)((v[k] - mean) * rstd * g[c + k] + bta[c + k]);
        *(bf16x4*)((bf16*)out + row * 512 + c) = o4;
    } else {
        f32x4 o4;
#pragma unroll
        for (int k = 0; k < 4; ++k) o4[k] = (v[k] - mean) * rstd * g[c + k] + bta[c + k];
        *(f32x4*)((float*)out + row * 512 + c) = o4;
    }
}

// ---------------------------------------------------------------------------
__global__ __launch_bounds__(256)
void transpose_cvt(const float* __restrict__ x, bf16* __restrict__ Xb, bf16* __restrict__ xt)
{
    __shared__ bf16 tile[32][33];
    const int b = blockIdx.z;
    const int n0 = blockIdx.x * 32, l0 = blockIdx.y * 32;
    const long base = (long)b * N_ID * L_IN;
    const int tx = threadIdx.x, ty = threadIdx.y;
#pragma unroll
    for (int i = ty; i < 32; i += 8) {
        const long idx = base + (long)(n0 + i) * L_IN + l0 + tx;
        const bf16 s = (bf16)x[idx];
        Xb[idx] = s;
        tile[i][tx] = s;
    }
    __syncthreads();
#pragma unroll
    for (int i = ty; i < 32; i += 8)
        xt[base + (long)(l0 + i) * N_ID + n0 + tx] = tile[tx][i];
}

__global__ void cvt_bf16(const float* __restrict__ in, bf16* __restrict__ out, int n)
{
    const int i = blockIdx.x * 256 + threadIdx.x;
    if (i < n) out[i] = (bf16)in[i];
}

__global__ void wo_sum(const float* __restrict__ Wo, bf16* __restrict__ out)
{
    const int i = blockIdx.x * 256 + threadIdx.x; // < 262144
    const float* p = Wo + (long)i * 8;
    float s = 0.f;
#pragma unroll
    for (int h = 0; h < 8; ++h) s += p[h];
    out[i] = (bf16)s;
}

__global__ void prep_scal(const float* __restrict__ W1, const float* __restrict__ b1, float* __restrict__ out)
{
    if (threadIdx.x == 0 && blockIdx.x == 0) {
        float s = 0.f;
        for (int h = 0; h < 8; ++h) s += W1[h];
        out[0] = s;
        out[1] = b1[0];
    }
}

// ---------------------------------------------------------------------------
static void launch_gemm(int epi, const bf16* A, const bf16* B, void* C,
                        const float* bc, const float* br, const void* res, const float* sc2,
                        float scale, int M, int N, int K,
                        long sA, long sB, long sC, long sRes, int batches, hipStream_t st)
{
    const unsigned gx = M / 256, gy = N / 256;
    const unsigned gxy = gx * gy, nwg = gxy * (unsigned)batches;
    dim3 g(nwg), blk(512);
    switch (epi) {
    case 0: gemm2<0><<<g, blk, 0, st>>>(A, B, C, bc, br, res, sc2, scale, N, K, sA, sB, sC, sRes, gx, gxy, nwg); break;
    case 1: gemm2<1><<<g, blk, 0, st>>>(A, B, C, bc, br, res, sc2, scale, N, K, sA, sB, sC, sRes, gx, gxy, nwg); break;
    case 2: gemm2<2><<<g, blk, 0, st>>>(A, B, C, bc, br, res, sc2, scale, N, K, sA, sB, sC, sRes, gx, gxy, nwg); break;
    case 3: gemm2<3><<<g, blk, 0, st>>>(A, B, C, bc, br, res, sc2, scale, N, K, sA, sB, sC, sRes, gx, gxy, nwg); break;
    case 4: gemm2<4><<<g, blk, 0, st>>>(A, B, C, bc, br, res, sc2, scale, N, K, sA, sB, sC, sRes, gx, gxy, nwg); break;
    case 5: gemm2<5><<<g, blk, 0, st>>>(A, B, C, bc, br, res, sc2, scale, N, K, sA, sB, sC, sRes, gx, gxy, nwg); break;
    default: gemm2<6><<<g, blk, 0, st>>>(A, B, C, bc, br, res, sc2, scale, N, K, sA, sB, sC, sRes, gx, gxy, nwg); break;
    }
}

extern "C" void kernel_launch(void* const* d_in, const int* in_sizes, int n_in,
                              void* d_out, int out_size, void* d_ws, size_t ws_size,
                              hipStream_t stream)
{
    (void)in_sizes; (void)n_in; (void)out_size;

    const float* x   = (const float*)d_in[0];
    const float* tWq = (const float*)d_in[1];  const float* tbq = (const float*)d_in[2];
    const float* tWk = (const float*)d_in[3];  const float* tbk = (const float*)d_in[4];
    const float* tWv = (const float*)d_in[5];  const float* tbv = (const float*)d_in[6];
    const float* tWo = (const float*)d_in[7];  const float* tbo = (const float*)d_in[8];
    const float* tg  = (const float*)d_in[9];  const float* tb  = (const float*)d_in[10];
    const float* cWq = (const float*)d_in[11]; const float* cbq = (const float*)d_in[12];
    const float* cWk = (const float*)d_in[13]; const float* cbk = (const float*)d_in[14];
    const float* cWv = (const float*)d_in[15]; const float* cbv = (const float*)d_in[16];
    const float* cWo = (const float*)d_in[17]; const float* cbo = (const float*)d_in[18];
    const float* cg  = (const float*)d_in[19]; const float* cb  = (const float*)d_in[20];
    const float* sWq = (const float*)d_in[21]; const float* sbq = (const float*)d_in[22];
    const float* sWk = (const float*)d_in[23]; const float* sbk = (const float*)d_in[24];
    const float* sWv = (const float*)d_in[25]; const float* sbv = (const float*)d_in[26];
    const float* sW1 = (const float*)d_in[27]; const float* sb1 = (const float*)d_in[28];

    char* p = (char*)d_ws;
    auto alloc = [&](size_t bytes) -> char* {
        char* r = p; p += (bytes + 255) & ~(size_t)255; return r;
    };

    bf16* WqT = (bf16*)alloc(262144 * 2);  bf16* WkT = (bf16*)alloc(262144 * 2);  bf16* WvT = (bf16*)alloc(262144 * 2);
    bf16* WqC = (bf16*)alloc(262144 * 2);  bf16* WkC = (bf16*)alloc(262144 * 2);  bf16* WvC = (bf16*)alloc(262144 * 2);
    bf16* WqS = (bf16*)alloc(1048576 * 2); bf16* WkS = (bf16*)alloc(1048576 * 2); bf16* WvS = (bf16*)alloc(1048576 * 2);
    bf16* WsT = (bf16*)alloc(262144 * 2);  bf16* WsC = (bf16*)alloc(262144 * 2);
    float* scal = (float*)alloc(256);

    const size_t ACT_B = (size_t)ACT_E * 2;
    bf16* Xb   = (bf16*)alloc(ACT_B);   // reused as SO after stage T
    bf16* xt   = (bf16*)alloc(ACT_B);
    bf16* bufQ = (bf16*)alloc(ACT_B);   // Q; Lm aliases this in attn loops
    bf16* bufK = (bf16*)alloc(ACT_B);
    bf16* bufV = (bf16*)alloc(ACT_B);
    bf16* TO   = (bf16*)alloc(ACT_B);

    // bf16 S/P buffer, softmax runs IN-PLACE (P aliases S): 2 MB/batch
    size_t used = (size_t)(p - (char*)d_ws);
    int CB = 32;
    while (CB > 1 && used + (size_t)CB * 2097152ULL + 4096 > ws_size) CB >>= 1;
    bf16* Sbuf = (bf16*)alloc((size_t)CB * 2097152ULL);
    bf16* Pbuf = Sbuf;

    const float rsc_t = 0.08838834764831845f;  // 1/sqrt(1024/8)
    const float rsc_s = 0.125f;                // 1/sqrt(512/8)

    // ---- prep ----
    cvt_bf16<<<dim3(1024), dim3(256), 0, stream>>>(tWq, WqT, 262144);
    cvt_bf16<<<dim3(1024), dim3(256), 0, stream>>>(tWk, WkT, 262144);
    cvt_bf16<<<dim3(1024), dim3(256), 0, stream>>>(tWv, WvT, 262144);
    cvt_bf16<<<dim3(1024), dim3(256), 0, stream>>>(cWq, WqC, 262144);
    cvt_bf16<<<dim3(1024), dim3(256), 0, stream>>>(cWk, WkC, 262144);
    cvt_bf16<<<dim3(1024), dim3(256), 0, stream>>>(cWv, WvC, 262144);
    cvt_bf16<<<dim3(4096), dim3(256), 0, stream>>>(sWq, WqS, 1048576);
    cvt_bf16<<<dim3(4096), dim3(256), 0, stream>>>(sWk, WkS, 1048576);
    cvt_bf16<<<dim3(4096), dim3(256), 0, stream>>>(sWv, WvS, 1048576);
    wo_sum<<<dim3(1024), dim3(256), 0, stream>>>(tWo, WsT);
    wo_sum<<<dim3(1024), dim3(256), 0, stream>>>(cWo, WsC);
    prep_scal<<<dim3(1), dim3(64), 0, stream>>>(sW1, sb1, scal);
    transpose_cvt<<<dim3(32, 16, BATCH), dim3(32, 8), 0, stream>>>(x, Xb, xt);

    auto attn_tc = [&](const bf16* Q, const bf16* Kb, const bf16* V, bf16* LmOut, float rsc) {
        for (int c0 = 0; c0 < BATCH; c0 += CB) {
            const long off = (long)c0 * S_NL;
            launch_gemm(2, Q + off, Kb + off, Sbuf, nullptr, nullptr, nullptr, nullptr, rsc,
                        1024, 1024, 512, S_NL, S_NL, S_TT, 0, CB, stream);
            softmax_rows<1024><<<dim3(CB * 1024), dim3(256), 0, stream>>>(Sbuf, Pbuf);
            launch_gemm(3, Pbuf, V + off, LmOut + off, nullptr, nullptr, nullptr, nullptr, 0.f,
                        1024, 512, 1024, S_TT, S_NL, S_NL, 0, CB, stream);
        }
    };

    // ==== Stage T (time de_att) ====
    launch_gemm(0, Xb, WqT, bufQ, tbq, nullptr, nullptr, nullptr, 0.f, 32768, 512, 512, 0, 0, 0, 0, 1, stream);
    launch_gemm(0, Xb, WkT, bufK, tbk, nullptr, nullptr, nullptr, 0.f, 32768, 512, 512, 0, 0, 0, 0, 1, stream);
    launch_gemm(1, WvT, Xb, bufV, nullptr, tbv, nullptr, nullptr, 0.f, 512, 1024, 512, 0, S_NL, S_NL, 0, BATCH, stream);
    attn_tc(bufQ, bufK, bufV, bufQ, rsc_t);
    launch_gemm(5, bufQ, WsT, d_out, tbo, nullptr, x, nullptr, 0.f, 32768, 512, 512, 0, 0, 0, 0, 1, stream);
    ln_rows<1><<<dim3(32768), dim3(128), 0, stream>>>((const float*)d_out, tg, tb, TO);

    // ==== Stage S (space attention) ====
    bf16* SOp = Xb;
    launch_gemm(0, xt, WqS, bufQ, sbq, nullptr, nullptr, nullptr, 0.f, 16384, 1024, 1024, 0, 0, 0, 0, 1, stream);
    launch_gemm(0, xt, WkS, bufK, sbk, nullptr, nullptr, nullptr, 0.f, 16384, 1024, 1024, 0, 0, 0, 0, 1, stream);
    launch_gemm(1, WvS, xt, bufV, nullptr, sbv, nullptr, nullptr, 0.f, 1024, 512, 1024, 0, S_NL, S_NL, 0, BATCH, stream);
    for (int c0 = 0; c0 < BATCH; c0 += CB) {
        const long off = (long)c0 * S_NL;
        launch_gemm(2, bufQ + off, bufK + off, Sbuf, nullptr, nullptr, nullptr, nullptr, rsc_s,
                    512, 512, 1024, S_NL, S_NL, S_SS2, 0, CB, stream);
        softmax_rows<512><<<dim3(CB * 512), dim3(256), 0, stream>>>(Sbuf, Pbuf);
        launch_gemm(4, bufV + off, Pbuf, SOp + off, nullptr, nullptr, nullptr, scal, 0.f,
                    1024, 512, 512, S_NL, S_SS2, S_NL, 0, CB, stream);
    }

    // ==== Stage C (cross de_att) ====
    launch_gemm(0, SOp, WqC, bufQ, cbq, nullptr, nullptr, nullptr, 0.f, 32768, 512, 512, 0, 0, 0, 0, 1, stream);
    launch_gemm(0, TO, WkC, bufK, cbk, nullptr, nullptr, nullptr, 0.f, 32768, 512, 512, 0, 0, 0, 0, 1, stream);
    launch_gemm(1, WvC, TO, bufV, nullptr, cbv, nullptr, nullptr, 0.f, 512, 1024, 512, 0, S_NL, S_NL, 0, BATCH, stream);
    attn_tc(bufQ, bufK, bufV, bufQ, rsc_t);
    launch_gemm(6, bufQ, WsC, d_out, cbo, nullptr, TO, nullptr, 0.f, 32768, 512, 512, 0, 0, 0, 0, 1, stream);
    ln_rows<0><<<dim3(32768), dim3(128), 0, stream>>>((const float*)d_out, cg, cb, d_out);
}

// Round 4
// 805.192 us; speedup vs baseline: 1.4741x; 1.0440x over previous
//
#include <hip/hip_runtime.h>
#include <hip/hip_bf16.h>

typedef __bf16 bf16;
typedef __bf16 bf16x8 __attribute__((ext_vector_type(8)));
typedef __bf16 bf16x4 __attribute__((ext_vector_type(4)));
typedef __bf16 bf16x2 __attribute__((ext_vector_type(2)));
typedef float f32x4 __attribute__((ext_vector_type(4)));
typedef float f32x2 __attribute__((ext_vector_type(2)));

#define BATCH 32
#define N_ID 1024
#define L_IN 512

static const long ACT_E = (long)BATCH * N_ID * L_IN;   // 16,777,216
static const long S_NL  = (long)N_ID * L_IN;           // 524288
static const long S_TT  = (long)N_ID * N_ID;           // 1048576
static const long S_SS2 = (long)L_IN * L_IN;           // 262144

__device__ __forceinline__ void gload16(const bf16* g, bf16* l)
{
    __builtin_amdgcn_global_load_lds((__attribute__((address_space(1))) void*)g,
                                     (__attribute__((address_space(3))) void*)l, 16, 0, 0);
}

// ---------------------------------------------------------------------------
// 128x128 BK=32 double-buffered counted 2-phase NT GEMM (4 blocks/CU).
// C[m,n] = sum_k A[m,k]*B[n,k]; lda=ldb=K, ldc=N; batch via swizzled 1-D grid.
// Per K-tile: issue 4 global_load_lds (next tile) -> 8 ds_read_b128 + 16 MFMA
// -> vmcnt(0) -> s_barrier.  TLP across 4 blocks/CU hides the drain.
// EPI: 0 bf16=acc+biasCol[n]; 1 bf16=acc+biasRow[m]; 2 bf16=acc*scale;
//      3 bf16=acc; 4 bf16=acc*scal2[0]+scal2[1]; 5 bf16=acc+ResBF16+biasCol[n]
// ---------------------------------------------------------------------------
#define VM0 asm volatile("s_waitcnt vmcnt(0)" ::: "memory")
#define BAR __builtin_amdgcn_s_barrier()

#define COMPUTE(BUF) \
    { \
      bf16x8 af[4], bfv[4]; \
_Pragma("unroll") \
      for (int i = 0; i < 4; ++i) \
        af[i] = *(const bf16x8*)&lds[BUF][0][(wm * 64 + i * 16 + fr) * 32 + slotk]; \
_Pragma("unroll") \
      for (int j = 0; j < 4; ++j) \
        bfv[j] = *(const bf16x8*)&lds[BUF][1][(wn * 64 + j * 16 + fr) * 32 + slotk]; \
_Pragma("unroll") \
      for (int i = 0; i < 4; ++i) \
_Pragma("unroll") \
        for (int j = 0; j < 4; ++j) \
          acc[i][j] = __builtin_amdgcn_mfma_f32_16x16x32_bf16(af[i], bfv[j], acc[i][j], 0, 0, 0); \
    }

#define STAGE(BUF, KT) { stg(BUF, 0, Ab, m0, KT); stg(BUF, 1, Bb, n0, KT); }

template<int EPI>
__global__ __launch_bounds__(256, 4)
void gemm2(const bf16* __restrict__ A, const bf16* __restrict__ Bm, void* __restrict__ Cout,
           const float* __restrict__ biasCol, const float* __restrict__ biasRow,
           const void* __restrict__ Res, const float* __restrict__ scal2,
           float scale, int N, int K,
           long sA, long sB, long sC, long sRes,
           unsigned gx, unsigned gxy, unsigned nwg)
{
    __shared__ __align__(16) bf16 lds[2][2][128 * 32];   // [buf][A/B] 8KB each

    // bijective XCD swizzle (m204)
    unsigned id = blockIdx.x;
    {
        const unsigned q = nwg >> 3, r = nwg & 7;
        const unsigned xcd = id & 7, off = id >> 3;
        id = (xcd < r ? xcd * (q + 1) : r * (q + 1) + (xcd - r) * q) + off;
    }
    const unsigned bz = id / gxy;
    const unsigned rem = id - bz * gxy;
    const unsigned by = rem / gx;
    const unsigned bx = rem - by * gx;

    const int t = threadIdx.x;
    const int w = t >> 6;
    const int lane = t & 63;
    const int fr = lane & 15;
    const int kg = lane >> 4;
    const int wm = w >> 1, wn = w & 1;
    const long z = bz;
    const long m0 = (long)bx * 128;
    const long n0 = (long)by * 128;
    const bf16* Ab = A + z * sA;
    const bf16* Bb = Bm + z * sB;

    // staging: srow = w*16 + lane/4 (rows 0..63, +64 on 2nd iter); 4 chunks/row
    const int srow = w * 16 + (lane >> 2);
    const int gc = (lane & 3) ^ ((lane >> 2) & 3);    // pre-swizzled global chunk
    const int slotk = (kg ^ (fr & 3)) * 8;            // read-side swizzle slot

    auto stg = [&](int buf, int ab, const bf16* base, long rc0, int kt) {
#pragma unroll
        for (int r = 0; r < 2; ++r) {
            const int row = r * 64 + srow;
            const bf16* src = base + (rc0 + row) * (long)K + kt * 32 + gc * 8;
            gload16(src, (bf16*)&lds[buf][ab][row * 32 + (lane & 3) * 8]);
        }
    };

    f32x4 acc[4][4] = {};

    STAGE(0, 0);
    VM0; BAR;

    const int NT = K >> 5;            // K % 64 == 0 -> NT even
    for (int kt = 0; kt < NT; kt += 2) {
        if (kt + 1 < NT) STAGE(1, kt + 1);
        COMPUTE(0);
        VM0; BAR;
        if (kt + 2 < NT) STAGE(0, kt + 2);
        COMPUTE(1);
        VM0; BAR;
    }

    float e0 = 0.f, e1 = 0.f;
    if constexpr (EPI == 4) { e0 = scal2[0]; e1 = scal2[1]; }

#pragma unroll
    for (int i = 0; i < 4; ++i) {
        const long rb = m0 + wm * 64 + i * 16 + kg * 4;
#pragma unroll
        for (int j = 0; j < 4; ++j) {
            const long cc = n0 + wn * 64 + j * 16 + fr;
#pragma unroll
            for (int r = 0; r < 4; ++r) {
                const long rr = rb + r;
                const float v = acc[i][j][r];
                const long idx = z * sC + rr * (long)N + cc;
                if constexpr (EPI == 0)      ((bf16*)Cout)[idx] = (bf16)(v + biasCol[cc]);
                else if constexpr (EPI == 1) ((bf16*)Cout)[idx] = (bf16)(v + biasRow[rr]);
                else if constexpr (EPI == 2) ((bf16*)Cout)[idx] = (bf16)(v * scale);
                else if constexpr (EPI == 3) ((bf16*)Cout)[idx] = (bf16)v;
                else if constexpr (EPI == 4) ((bf16*)Cout)[idx] = (bf16)(v * e0 + e1);
                else ((bf16*)Cout)[idx] = (bf16)(v + (float)((const bf16*)Res)[z * sRes + rr * (long)N + cc] + biasCol[cc]);
            }
        }
    }
}

// ---------------------------------------------------------------------------
// Row softmax, bf16 in -> bf16 out, IN-PLACE (P aliases S). Scale pre-applied.
// ---------------------------------------------------------------------------
template<int W>
__global__ __launch_bounds__(256)
void softmax_rows(const bf16* __restrict__ S, bf16* __restrict__ P)
{
    constexpr int NV = W / 256;
    const long row = blockIdx.x;
    const int t = threadIdx.x;
    const bf16* src = S + row * (long)W + t * NV;
    bf16* dst = P + row * (long)W + t * NV;

    float v[NV];
    if constexpr (NV == 4) { bf16x4 x = *(const bf16x4*)src;
        v[0] = (float)x[0]; v[1] = (float)x[1]; v[2] = (float)x[2]; v[3] = (float)x[3]; }
    else { bf16x2 x = *(const bf16x2*)src; v[0] = (float)x[0]; v[1] = (float)x[1]; }

    float m = v[0];
#pragma unroll
    for (int i = 1; i < NV; ++i) m = fmaxf(m, v[i]);
#pragma unroll
    for (int o = 32; o > 0; o >>= 1) m = fmaxf(m, __shfl_xor(m, o));
    __shared__ float red[8];
    const int w = t >> 6, l = t & 63;
    if (l == 0) red[w] = m;
    __syncthreads();
    m = fmaxf(fmaxf(red[0], red[1]), fmaxf(red[2], red[3]));

    float s = 0.f;
#pragma unroll
    for (int i = 0; i < NV; ++i) { v[i] = __expf(v[i] - m); s += v[i]; }
#pragma unroll
    for (int o = 32; o > 0; o >>= 1) s += __shfl_xor(s, o);
    if (l == 0) red[4 + w] = s;
    __syncthreads();
    s = red[4] + red[5] + red[6] + red[7];
    const float inv = 1.f / s;

    if constexpr (NV == 4) {
        bf16x4 o4;
#pragma unroll
        for (int i = 0; i < 4; ++i) o4[i] = (bf16)(v[i] * inv);
        *(bf16x4*)dst = o4;
    } else {
        bf16x2 o2;
#pragma unroll
        for (int i = 0; i < 2; ++i) o2[i] = (bf16)(v[i] * inv);
        *(bf16x2*)dst = o2;
    }
}

// ---------------------------------------------------------------------------
// LayerNorm over rows of 512, bf16 in. OUTBF=1 -> bf16 out, else f32 out.
// ---------------------------------------------------------------------------
template<int OUTBF>
__global__ __launch_bounds__(128)
void ln_rows(const bf16* __restrict__ X, const float* __restrict__ g,
             const float* __restrict__ bta, void* __restrict__ out)
{
    const long row = blockIdx.x;
    const int t = threadIdx.x;
    bf16x4 b4 = *(const bf16x4*)(X + row * 512 + t * 4);
    float v[4] = { (float)b4[0], (float)b4[1], (float)b4[2], (float)b4[3] };
    float s1 = v[0] + v[1] + v[2] + v[3];
    float s2 = v[0]*v[0] + v[1]*v[1] + v[2]*v[2] + v[3]*v[3];
#pragma unroll
    for (int o = 32; o > 0; o >>= 1) { s1 += __shfl_xor(s1, o); s2 += __shfl_xor(s2, o); }
    __shared__ float r1[2], r2[2];
    const int w = t >> 6, l = t & 63;
    if (l == 0) { r1[w] = s1; r2[w] = s2; }
    __syncthreads();
    s1 = r1[0] + r1[1];
    s2 = r2[0] + r2[1];
    const float mean = s1 * (1.f / 512.f);
    const float var  = s2 * (1.f / 512.f) - mean * mean;
    const float rstd = rsqrtf(var + 1e-5f);
    const int c = t * 4;
    if constexpr (OUTBF) {
        bf16x4 o4;
#pragma unroll
        for (int k = 0; k < 4; ++k) o4[k] = (bf16)((v[k] - mean) * rstd * g[c + k] + bta[c + k]);
        *(bf16x4*)((bf16*)out + row * 512 + c) = o4;
    } else {
        f32x4 o4;
#pragma unroll
        for (int k = 0; k < 4; ++k) o4[k] = (v[k] - mean) * rstd * g[c + k] + bta[c + k];
        *(f32x4*)((float*)out + row * 512 + c) = o4;
    }
}

// ---------------------------------------------------------------------------
__global__ __launch_bounds__(256)
void transpose_cvt(const float* __restrict__ x, bf16* __restrict__ Xb, bf16* __restrict__ xt)
{
    __shared__ bf16 tile[32][33];
    const int b = blockIdx.z;
    const int n0 = blockIdx.x * 32, l0 = blockIdx.y * 32;
    const long base = (long)b * N_ID * L_IN;
    const int tx = threadIdx.x, ty = threadIdx.y;
#pragma unroll
    for (int i = ty; i < 32; i += 8) {
        const long idx = base + (long)(n0 + i) * L_IN + l0 + tx;
        const bf16 s = (bf16)x[idx];
        Xb[idx] = s;
        tile[i][tx] = s;
    }
    __syncthreads();
#pragma unroll
    for (int i = ty; i < 32; i += 8)
        xt[base + (long)(l0 + i) * N_ID + n0 + tx] = tile[tx][i];
}

struct Ptr6 { const float* s[6]; bf16* d[6]; };

__global__ void cvt_multi(Ptr6 p, int n)   // n multiple of 1024; 4 elems/thread
{
    const int j = blockIdx.y;
    const int i = (blockIdx.x * 256 + threadIdx.x) * 4;
    if (i < n) {
        f32x4 v = *(const f32x4*)(p.s[j] + i);
        bf16x4 o; o[0] = (bf16)v[0]; o[1] = (bf16)v[1]; o[2] = (bf16)v[2]; o[3] = (bf16)v[3];
        *(bf16x4*)(p.d[j] + i) = o;
    }
}

// Wo [512,512,1,8] -> bf16 [512,512] summed over head axis; 2 jobs via y
__global__ void wo_sum2(const float* __restrict__ a, const float* __restrict__ b,
                        bf16* __restrict__ da, bf16* __restrict__ db)
{
    const int i = blockIdx.x * 256 + threadIdx.x; // < 262144
    const float* src = blockIdx.y ? b : a;
    bf16* dst = blockIdx.y ? db : da;
    const float* p = src + (long)i * 8;
    float s = 0.f;
#pragma unroll
    for (int h = 0; h < 8; ++h) s += p[h];
    dst[i] = (bf16)s;
}

__global__ void prep_scal(const float* __restrict__ W1, const float* __restrict__ b1, float* __restrict__ out)
{
    if (threadIdx.x == 0 && blockIdx.x == 0) {
        float s = 0.f;
        for (int h = 0; h < 8; ++h) s += W1[h];
        out[0] = s;
        out[1] = b1[0];
    }
}

// ---------------------------------------------------------------------------
static void launch_gemm(int epi, const bf16* A, const bf16* B, void* C,
                        const float* bc, const float* br, const void* res, const float* sc2,
                        float scale, int M, int N, int K,
                        long sA, long sB, long sC, long sRes, int batches, hipStream_t st)
{
    const unsigned gx = M / 128, gy = N / 128;
    const unsigned gxy = gx * gy, nwg = gxy * (unsigned)batches;
    dim3 g(nwg), blk(256);
    switch (epi) {
    case 0: gemm2<0><<<g, blk, 0, st>>>(A, B, C, bc, br, res, sc2, scale, N, K, sA, sB, sC, sRes, gx, gxy, nwg); break;
    case 1: gemm2<1><<<g, blk, 0, st>>>(A, B, C, bc, br, res, sc2, scale, N, K, sA, sB, sC, sRes, gx, gxy, nwg); break;
    case 2: gemm2<2><<<g, blk, 0, st>>>(A, B, C, bc, br, res, sc2, scale, N, K, sA, sB, sC, sRes, gx, gxy, nwg); break;
    case 3: gemm2<3><<<g, blk, 0, st>>>(A, B, C, bc, br, res, sc2, scale, N, K, sA, sB, sC, sRes, gx, gxy, nwg); break;
    case 4: gemm2<4><<<g, blk, 0, st>>>(A, B, C, bc, br, res, sc2, scale, N, K, sA, sB, sC, sRes, gx, gxy, nwg); break;
    default: gemm2<5><<<g, blk, 0, st>>>(A, B, C, bc, br, res, sc2, scale, N, K, sA, sB, sC, sRes, gx, gxy, nwg); break;
    }
}

extern "C" void kernel_launch(void* const* d_in, const int* in_sizes, int n_in,
                              void* d_out, int out_size, void* d_ws, size_t ws_size,
                              hipStream_t stream)
{
    (void)in_sizes; (void)n_in; (void)out_size;

    const float* x   = (const float*)d_in[0];
    const float* tWq = (const float*)d_in[1];  const float* tbq = (const float*)d_in[2];
    const float* tWk = (const float*)d_in[3];  const float* tbk = (const float*)d_in[4];
    const float* tWv = (const float*)d_in[5];  const float* tbv = (const float*)d_in[6];
    const float* tWo = (const float*)d_in[7];  const float* tbo = (const float*)d_in[8];
    const float* tg  = (const float*)d_in[9];  const float* tb  = (const float*)d_in[10];
    const float* cWq = (const float*)d_in[11]; const float* cbq = (const float*)d_in[12];
    const float* cWk = (const float*)d_in[13]; const float* cbk = (const float*)d_in[14];
    const float* cWv = (const float*)d_in[15]; const float* cbv = (const float*)d_in[16];
    const float* cWo = (const float*)d_in[17]; const float* cbo = (const float*)d_in[18];
    const float* cg  = (const float*)d_in[19]; const float* cb  = (const float*)d_in[20];
    const float* sWq = (const float*)d_in[21]; const float* sbq = (const float*)d_in[22];
    const float* sWk = (const float*)d_in[23]; const float* sbk = (const float*)d_in[24];
    const float* sWv = (const float*)d_in[25]; const float* sbv = (const float*)d_in[26];
    const float* sW1 = (const float*)d_in[27]; const float* sb1 = (const float*)d_in[28];

    char* p = (char*)d_ws;
    auto alloc = [&](size_t bytes) -> char* {
        char* r = p; p += (bytes + 255) & ~(size_t)255; return r;
    };

    bf16* WqT = (bf16*)alloc(262144 * 2);  bf16* WkT = (bf16*)alloc(262144 * 2);  bf16* WvT = (bf16*)alloc(262144 * 2);
    bf16* WqC = (bf16*)alloc(262144 * 2);  bf16* WkC = (bf16*)alloc(262144 * 2);  bf16* WvC = (bf16*)alloc(262144 * 2);
    bf16* WqS = (bf16*)alloc(1048576 * 2); bf16* WkS = (bf16*)alloc(1048576 * 2); bf16* WvS = (bf16*)alloc(1048576 * 2);
    bf16* WsT = (bf16*)alloc(262144 * 2);  bf16* WsC = (bf16*)alloc(262144 * 2);
    float* scal = (float*)alloc(256);

    const size_t ACT_B = (size_t)ACT_E * 2;
    bf16* Xb   = (bf16*)alloc(ACT_B);   // reused as SO after stage T
    bf16* xt   = (bf16*)alloc(ACT_B);
    bf16* bufQ = (bf16*)alloc(ACT_B);   // Q; Lm aliases this in attn loops
    bf16* bufK = (bf16*)alloc(ACT_B);   // K; reused as preLN scratch after attn
    bf16* bufV = (bf16*)alloc(ACT_B);
    bf16* TO   = (bf16*)alloc(ACT_B);

    size_t used = (size_t)(p - (char*)d_ws);
    int CB = 32;
    while (CB > 1 && used + (size_t)CB * 2097152ULL + 4096 > ws_size) CB >>= 1;
    bf16* Sbuf = (bf16*)alloc((size_t)CB * 2097152ULL);
    bf16* Pbuf = Sbuf;   // softmax in-place

    const float rsc_t = 0.08838834764831845f;  // 1/sqrt(1024/8)
    const float rsc_s = 0.125f;                // 1/sqrt(512/8)

    // ---- prep (fused launches) ----
    Ptr6 smallW; 
    smallW.s[0] = tWq; smallW.s[1] = tWk; smallW.s[2] = tWv;
    smallW.s[3] = cWq; smallW.s[4] = cWk; smallW.s[5] = cWv;
    smallW.d[0] = WqT; smallW.d[1] = WkT; smallW.d[2] = WvT;
    smallW.d[3] = WqC; smallW.d[4] = WkC; smallW.d[5] = WvC;
    cvt_multi<<<dim3(256, 6), dim3(256), 0, stream>>>(smallW, 262144);
    Ptr6 bigW = {};
    bigW.s[0] = sWq; bigW.s[1] = sWk; bigW.s[2] = sWv;
    bigW.d[0] = WqS; bigW.d[1] = WkS; bigW.d[2] = WvS;
    cvt_multi<<<dim3(1024, 3), dim3(256), 0, stream>>>(bigW, 1048576);
    wo_sum2<<<dim3(1024, 2), dim3(256), 0, stream>>>(tWo, cWo, WsT, WsC);
    prep_scal<<<dim3(1), dim3(64), 0, stream>>>(sW1, sb1, scal);
    transpose_cvt<<<dim3(32, 16, BATCH), dim3(32, 8), 0, stream>>>(x, Xb, xt);

    auto attn_tc = [&](const bf16* Q, const bf16* Kb, const bf16* V, bf16* LmOut, float rsc) {
        for (int c0 = 0; c0 < BATCH; c0 += CB) {
            const long off = (long)c0 * S_NL;
            launch_gemm(2, Q + off, Kb + off, Sbuf, nullptr, nullptr, nullptr, nullptr, rsc,
                        1024, 1024, 512, S_NL, S_NL, S_TT, 0, CB, stream);
            softmax_rows<1024><<<dim3(CB * 1024), dim3(256), 0, stream>>>(Sbuf, Pbuf);
            launch_gemm(3, Pbuf, V + off, LmOut + off, nullptr, nullptr, nullptr, nullptr, 0.f,
                        1024, 512, 1024, S_TT, S_NL, S_NL, 0, CB, stream);
        }
    };

    // ==== Stage T (time de_att) ====
    launch_gemm(0, Xb, WqT, bufQ, tbq, nullptr, nullptr, nullptr, 0.f, 32768, 512, 512, 0, 0, 0, 0, 1, stream);
    launch_gemm(0, Xb, WkT, bufK, tbk, nullptr, nullptr, nullptr, 0.f, 32768, 512, 512, 0, 0, 0, 0, 1, stream);
    launch_gemm(1, WvT, Xb, bufV, nullptr, tbv, nullptr, nullptr, 0.f, 512, 1024, 512, 0, S_NL, S_NL, 0, BATCH, stream);
    attn_tc(bufQ, bufK, bufV, bufQ, rsc_t);
    // preLN (bf16) = Lm @ WsT^T + Xb + tbo  -> bufK; then LN -> TO (bf16)
    launch_gemm(5, bufQ, WsT, bufK, tbo, nullptr, Xb, nullptr, 0.f, 32768, 512, 512, 0, 0, 0, 0, 1, stream);
    ln_rows<1><<<dim3(32768), dim3(128), 0, stream>>>(bufK, tg, tb, TO);

    // ==== Stage S (space attention) ====
    bf16* SOp = Xb;   // Xb dead after stage T -> reuse for space_out
    launch_gemm(0, xt, WqS, bufQ, sbq, nullptr, nullptr, nullptr, 0.f, 16384, 1024, 1024, 0, 0, 0, 0, 1, stream);
    launch_gemm(0, xt, WkS, bufK, sbk, nullptr, nullptr, nullptr, 0.f, 16384, 1024, 1024, 0, 0, 0, 0, 1, stream);
    launch_gemm(1, WvS, xt, bufV, nullptr, sbv, nullptr, nullptr, 0.f, 1024, 512, 1024, 0, S_NL, S_NL, 0, BATCH, stream);
    for (int c0 = 0; c0 < BATCH; c0 += CB) {
        const long off = (long)c0 * S_NL;
        launch_gemm(2, bufQ + off, bufK + off, Sbuf, nullptr, nullptr, nullptr, nullptr, rsc_s,
                    512, 512, 1024, S_NL, S_NL, S_SS2, 0, CB, stream);
        softmax_rows<512><<<dim3(CB * 512), dim3(256), 0, stream>>>(Sbuf, Pbuf);
        launch_gemm(4, bufV + off, Pbuf, SOp + off, nullptr, nullptr, nullptr, scal, 0.f,
                    1024, 512, 512, S_NL, S_SS2, S_NL, 0, CB, stream);
    }

    // ==== Stage C (cross de_att) ====
    launch_gemm(0, SOp, WqC, bufQ, cbq, nullptr, nullptr, nullptr, 0.f, 32768, 512, 512, 0, 0, 0, 0, 1, stream);
    launch_gemm(0, TO, WkC, bufK, cbk, nullptr, nullptr, nullptr, 0.f, 32768, 512, 512, 0, 0, 0, 0, 1, stream);
    launch_gemm(1, WvC, TO, bufV, nullptr, cbv, nullptr, nullptr, 0.f, 512, 1024, 512, 0, S_NL, S_NL, 0, BATCH, stream);
    attn_tc(bufQ, bufK, bufV, bufQ, rsc_t);
    // preLN (bf16) -> bufK; final LN -> f32 d_out
    launch_gemm(5, bufQ, WsC, bufK, cbo, nullptr, TO, nullptr, 0.f, 32768, 512, 512, 0, 0, 0, 0, 1, stream);
    ln_rows<0><<<dim3(32768), dim3(128), 0, stream>>>(bufK, cg, cb, d_out);
}